// Round 6
// baseline (608.341 us; speedup 1.0000x reference)
//
#include <hip/hip_runtime.h>
#include <cstdint>
#include <cstddef>

#define N_NODES 100000
#define N_EDGES 3200000
#define N_FEAT  512
#define HIDDEN  16
#define NBUCK   ((N_NODES + 127) / 128)   // 782 buckets of 128 rows
#define BCAP    5120                      // slots/bucket; mean 4096, +16 sigma
#define CHUNK   4096                      // edges per binscatter block

// ---------------------------------------------------------------------------
// Prep: build W1^T (16 x 512) for coalesced per-lane float4 loads, and zero
// the bucket cursors (replaces hipMemsetAsync / rocclr fillBuffer).
__global__ __launch_bounds__(256)
void k_prep(const float* __restrict__ W1, float* __restrict__ W1T,
            int* __restrict__ cursor) {
  const int i = blockIdx.x * 256 + threadIdx.x;
  if (i < N_FEAT * HIDDEN) {
    const int k = i >> 4, c = i & 15;
    W1T[(size_t)c * N_FEAT + k] = W1[i];
  }
  if (i < NBUCK) cursor[i] = 0;
}

// ---------------------------------------------------------------------------
// Kernel 1: xw[r][c] = sum_k x[r][k] * W1[k][c]    (512-K dot, 16 outputs)
// Mapping: 16 lanes per row, lane16 = output column c. x row is loaded as
// float4 broadcast within the 16-lane group (16 sectors/wave, L1-reused);
// W1^T row per lane as float4 (32 KB, L1-resident). No LDS, ~30 VGPR ->
// full occupancy; pure streaming, HBM-bound.
__global__ __launch_bounds__(256)
void k_gemm1(const float* __restrict__ x, const float* __restrict__ W1T,
             float* __restrict__ xw) {
  const int t = threadIdx.x;
  const int c = t & 15;
  const int r = blockIdx.x * 16 + (t >> 4);
  if (r >= N_NODES) return;
  const float* __restrict__ xr = x + (size_t)r * N_FEAT;
  const float* __restrict__ wc = W1T + (size_t)c * N_FEAT;
  float acc = 0.f;
#pragma unroll 1
  for (int k = 0; k < N_FEAT; k += 16) {
    const float4 xa = *(const float4*)(xr + k);
    const float4 xb = *(const float4*)(xr + k + 4);
    const float4 xc = *(const float4*)(xr + k + 8);
    const float4 xd = *(const float4*)(xr + k + 12);
    const float4 wa = *(const float4*)(wc + k);
    const float4 wb = *(const float4*)(wc + k + 4);
    const float4 wcv = *(const float4*)(wc + k + 8);
    const float4 wd = *(const float4*)(wc + k + 12);
    acc = fmaf(xa.x, wa.x, acc);  acc = fmaf(xa.y, wa.y, acc);
    acc = fmaf(xa.z, wa.z, acc);  acc = fmaf(xa.w, wa.w, acc);
    acc = fmaf(xb.x, wb.x, acc);  acc = fmaf(xb.y, wb.y, acc);
    acc = fmaf(xb.z, wb.z, acc);  acc = fmaf(xb.w, wb.w, acc);
    acc = fmaf(xc.x, wcv.x, acc); acc = fmaf(xc.y, wcv.y, acc);
    acc = fmaf(xc.z, wcv.z, acc); acc = fmaf(xc.w, wcv.w, acc);
    acc = fmaf(xd.x, wd.x, acc);  acc = fmaf(xd.y, wd.y, acc);
    acc = fmaf(xd.z, wd.z, acc);  acc = fmaf(xd.w, wd.w, acc);
  }
  xw[(size_t)r * 16 + c] = acc;
}

// ---------------------------------------------------------------------------
// Bucket edges by row>>7 (782 buckets of 128 rows). Per 4096-edge block:
// LDS stash + LDS histogram, ~780 block-aggregated global cursor atomics,
// then scatter of packed {col | (row&127)<<20, val_bits} into bucket slots.
__global__ __launch_bounds__(256)
void k_binscatter(const int* __restrict__ rows, const int* __restrict__ cols,
                  const float* __restrict__ vals, int* __restrict__ cursor,
                  int2* __restrict__ binned) {
  __shared__ int2 stash[CHUNK];                 // 32 KB
  __shared__ unsigned short sbuck[CHUNK];       // 8 KB
  __shared__ int hist[NBUCK];                   // 3.1 KB
  __shared__ int base[NBUCK];                   // 3.1 KB
  const int t = threadIdx.x;
  const int e0 = blockIdx.x * CHUNK;
  const int nv = (N_EDGES - e0 < CHUNK) ? (N_EDGES - e0) : CHUNK;

  for (int b = t; b < NBUCK; b += 256) hist[b] = 0;
  __syncthreads();

#pragma unroll
  for (int i = 0; i < CHUNK / 256; ++i) {
    const int idx = i * 256 + t;
    if (idx < nv) {
      const int e = e0 + idx;
      const int r = rows[e], c = cols[e];
      const float v = vals[e];
      const int b = r >> 7;
      stash[idx] = make_int2(c | ((r & 127) << 20), __float_as_int(v));
      sbuck[idx] = (unsigned short)b;
      atomicAdd(&hist[b], 1);                   // LDS atomic
    }
  }
  __syncthreads();

  for (int b = t; b < NBUCK; b += 256) {
    const int h = hist[b];
    base[b] = (h > 0) ? atomicAdd(&cursor[b], h) : 0;   // global, aggregated
    hist[b] = 0;                                         // reuse as rank ctr
  }
  __syncthreads();

#pragma unroll
  for (int i = 0; i < CHUNK / 256; ++i) {
    const int idx = i * 256 + t;
    if (idx < nv) {
      const int b = sbuck[idx];
      const int off = base[b] + atomicAdd(&hist[b], 1);  // LDS atomic
      if (off < BCAP) binned[(size_t)b * BCAP + off] = stash[idx];
    }
  }
}

// ---------------------------------------------------------------------------
// Per-bucket in-place counting sort -> bucket-local CSR + row_beg/row_end.
// All LDS: stash + rank via LDS atomics + 128-wide scan. Zero global atomics.
__global__ __launch_bounds__(256)
void k_localcsr(int2* __restrict__ binned, const int* __restrict__ cursor,
                int* __restrict__ row_beg, int* __restrict__ row_end) {
  __shared__ int2 stash[BCAP];                  // 40 KB
  __shared__ unsigned short rk[BCAP];           // 10 KB
  __shared__ int hist[128];
  __shared__ int pfx[128];
  const int t = threadIdx.x;
  const int b = blockIdx.x;
  const int raw = cursor[b];
  const int cnt = raw < BCAP ? raw : BCAP;
  int2* ep = binned + (size_t)b * BCAP;

  if (t < 128) hist[t] = 0;
  __syncthreads();

  for (int i = t; i < cnt; i += 256) {
    const int2 e = ep[i];
    stash[i] = e;
    rk[i] = (unsigned short)atomicAdd(&hist[(e.x >> 20) & 127], 1);
  }
  __syncthreads();

  if (t < 128) pfx[t] = hist[t];
  __syncthreads();
#pragma unroll
  for (int off = 1; off < 128; off <<= 1) {     // inclusive Hillis-Steele
    int add = (t >= off && t < 128) ? pfx[t - off] : 0;
    __syncthreads();
    if (t < 128) pfx[t] += add;
    __syncthreads();
  }

  if (t < 128) {
    const int r = b * 128 + t;
    if (r < N_NODES) {
      const int beg = b * BCAP + pfx[t] - hist[t];      // exclusive prefix
      row_beg[r] = beg;
      row_end[r] = beg + hist[t];
    }
  }
  __syncthreads();

  for (int i = t; i < cnt; i += 256) {
    const int2 e = stash[i];
    const int row = (e.x >> 20) & 127;
    ep[pfx[row] - hist[row] + (int)rk[i]] = e;
  }
}

// ---------------------------------------------------------------------------
// Fused layer-1 tail: gather-SPMM + bias + relu + (.) @ W2 -> hw1[r].
// 16 lanes per row (lane = hidden channel), 16 rows per 256-thread block.
__global__ __launch_bounds__(256)
void k_fused1(const int2* __restrict__ binned, const int* __restrict__ row_beg,
              const int* __restrict__ row_end, const float* __restrict__ xw,
              const float* __restrict__ b1, const float* __restrict__ W2,
              float* __restrict__ hw1) {
  const int t = threadIdx.x;
  const int lane16 = t & 15;
  const int r = blockIdx.x * 16 + (t >> 4);
  if (r >= N_NODES) return;
  const int s = row_beg[r], e = row_end[r];
  float a0 = 0.f, a1 = 0.f;
  int i = s;
  for (; i + 1 < e; i += 2) {                        // 2 independent chains
    int2 ea = binned[i], eb = binned[i + 1];
    a0 = fmaf(__int_as_float(ea.y), xw[(size_t)(ea.x & 0xFFFFF) * 16 + lane16], a0);
    a1 = fmaf(__int_as_float(eb.y), xw[(size_t)(eb.x & 0xFFFFF) * 16 + lane16], a1);
  }
  if (i < e) {
    int2 ea = binned[i];
    a0 = fmaf(__int_as_float(ea.y), xw[(size_t)(ea.x & 0xFFFFF) * 16 + lane16], a0);
  }
  float h = fmaxf(a0 + a1 + b1[lane16], 0.f);
  float p = h * W2[lane16];
#pragma unroll
  for (int m = 8; m >= 1; m >>= 1) p += __shfl_xor(p, m, 16);
  if (lane16 == 0) hw1[r] = p;
}

// ---------------------------------------------------------------------------
// Fused layer-2 tail: gather-SPMM on scalars + bias + sigmoid -> out[r].
__global__ __launch_bounds__(256)
void k_fused2(const int2* __restrict__ binned, const int* __restrict__ row_beg,
              const int* __restrict__ row_end, const float* __restrict__ hw1,
              const float* __restrict__ b2, float* __restrict__ out) {
  const int t = threadIdx.x;
  const int lane16 = t & 15;
  const int r = blockIdx.x * 16 + (t >> 4);
  if (r >= N_NODES) return;
  const int s = row_beg[r], e = row_end[r];
  float acc = 0.f;
  for (int i = s + lane16; i < e; i += 16) {
    int2 ev = binned[i];
    acc = fmaf(__int_as_float(ev.y), hw1[ev.x & 0xFFFFF], acc);
  }
#pragma unroll
  for (int m = 8; m >= 1; m >>= 1) acc += __shfl_xor(acc, m, 16);
  if (lane16 == 0) out[r] = 1.f / (1.f + expf(-(acc + b2[0])));
}

// ---------------------------------------------------------------------------
extern "C" void kernel_launch(void* const* d_in, const int* in_sizes, int n_in,
                              void* d_out, int out_size, void* d_ws, size_t ws_size,
                              hipStream_t stream) {
  const float* x    = (const float*)d_in[0];
  const float* vals = (const float*)d_in[1];
  const float* W1   = (const float*)d_in[2];
  const float* b1   = (const float*)d_in[3];
  const float* W2   = (const float*)d_in[4];
  const float* b2   = (const float*)d_in[5];
  const int*   rows = (const int*)d_in[6];
  const int*   cols = (const int*)d_in[7];
  float* out = (float*)d_out;

  // workspace: xw[N*16]f (6.4MB) | binned[NBUCK*BCAP]int2 (32.0MB) |
  //   cursor[NBUCK]i | row_beg[N]i | row_end[N]i | hw1[N]f | W1T[16*512]f
  char* w = (char*)d_ws;
  float* xw      = (float*)w;  w += (size_t)N_NODES * 16 * 4;
  int2*  binned  = (int2*)w;   w += (size_t)NBUCK * BCAP * 8;
  int*   cursor  = (int*)w;    w += (size_t)((NBUCK + 3) & ~3) * 4;
  int*   row_beg = (int*)w;    w += (size_t)N_NODES * 4;
  int*   row_end = (int*)w;    w += (size_t)N_NODES * 4;
  float* hw1     = (float*)w;  w += (size_t)N_NODES * 4;
  float* W1T     = (float*)w;

  k_prep      <<<32,                            256, 0, stream>>>(W1, W1T, cursor);
  k_gemm1     <<<(N_NODES + 15) / 16,           256, 0, stream>>>(x, W1T, xw);
  k_binscatter<<<(N_EDGES + CHUNK - 1) / CHUNK, 256, 0, stream>>>(rows, cols, vals,
                                                                  cursor, binned);
  k_localcsr  <<<NBUCK,                         256, 0, stream>>>(binned, cursor,
                                                                  row_beg, row_end);
  k_fused1    <<<(N_NODES + 15) / 16,           256, 0, stream>>>(binned, row_beg,
                                                                  row_end, xw, b1,
                                                                  W2, hw1);
  k_fused2    <<<(N_NODES + 15) / 16,           256, 0, stream>>>(binned, row_beg,
                                                                  row_end, hw1,
                                                                  b2, out);
}

// Round 7
// 218.089 us; speedup vs baseline: 2.7894x; 2.7894x over previous
//
#include <hip/hip_runtime.h>
#include <cstdint>
#include <cstddef>

#define N_NODES 100000
#define N_EDGES 3200000
#define N_FEAT  512
#define HIDDEN  16
#define NBUCK   ((N_NODES + 127) / 128)   // 782 buckets of 128 rows
#define BCAP    5120                      // slots/bucket; mean 4096, +16 sigma
#define CHUNK   4096                      // edges per binscatter block

// ---------------------------------------------------------------------------
// async global -> LDS, 16B per lane. LDS dest is wave-uniform base + lane*16.
__device__ __forceinline__ void gload_lds16(const float* g, void* lds) {
  __builtin_amdgcn_global_load_lds(
      (const __attribute__((address_space(1))) void*)g,
      (__attribute__((address_space(3))) void*)lds, 16, 0, 0);
}

// ---------------------------------------------------------------------------
// Prep: zero bucket cursors (replaces rocclr fillBuffer).
__global__ __launch_bounds__(256)
void k_prep(int* __restrict__ cursor) {
  const int i = blockIdx.x * 256 + threadIdx.x;
  if (i < NBUCK) cursor[i] = 0;
}

// ---------------------------------------------------------------------------
// Kernel 1: xw[r][c] = sum_k x[r][k] * W1[k][c]
// 256 thr = 4 waves; 64 rows/block; wave w covers k in [w*128, w*128+128).
// Each wave: private double-buffered LDS stage (4 KB/buf) filled by 4x
// global_load_lds (16B/lane), counted vmcnt(4), NO intra-loop barriers.
// Cross-wave partial-sum reduce via LDS at the end (single barrier).
// Swizzle (64 B row stride): slot(row r, pos p) holds global quad p^((r>>1)&3);
// write side applies the inverse on the global source address.
__global__ __launch_bounds__(256)
void k_gemm1(const float* __restrict__ x, const float* __restrict__ W1,
             float* __restrict__ xw) {
  __shared__ float4 xs[4][2][256];       // [wave][dbuf][64 rows x 4 quads] = 32 KB
  const int t = threadIdx.x;
  const int l = t & 63;                  // lane = row within block (compute phase)
  const int w = __builtin_amdgcn_readfirstlane(t >> 6);   // wave id -> SGPR
  const int rbase = blockIdx.x * 64;
  const int kbase0 = w * 128;

  float acc[16];
#pragma unroll
  for (int c = 0; c < 16; ++c) acc[c] = 0.f;

  const int sq   = ((l & 3) ^ ((l >> 3) & 3)) * 4;  // source quad offset (floats)
  const int srow = l >> 2;                          // row within 16-row group

  auto STAGE = [&](int b, int ck) {
    const int kb = kbase0 + ck * 16;
#pragma unroll
    for (int i = 0; i < 4; ++i) {
      int grow = rbase + i * 16 + srow;
      if (grow >= N_NODES) grow = N_NODES - 1;      // clamp: fixed instr count
      gload_lds16(x + (size_t)grow * N_FEAT + kb + sq, &xs[w][b][i * 64]);
    }
  };

  const int rsw = (l >> 1) & 3;                     // read swizzle for row l
  auto COMPUTE = [&](int b, int ck) {
    const int kb = kbase0 + ck * 16;
#pragma unroll
    for (int q = 0; q < 4; ++q) {
      float4 xv = xs[w][b][l * 4 + (q ^ rsw)];
      float xe[4] = {xv.x, xv.y, xv.z, xv.w};
#pragma unroll
      for (int j = 0; j < 4; ++j) {
        const float* wrow = W1 + (size_t)(kb + q * 4 + j) * 16;  // uniform -> s_load
#pragma unroll
        for (int c = 0; c < 16; ++c)
          acc[c] = fmaf(xe[j], wrow[c], acc[c]);
      }
    }
  };

  STAGE(0, 0);
#pragma unroll 1
  for (int ck = 0; ck < 8; ++ck) {
    const int b = ck & 1;
    if (ck + 1 < 8) {
      STAGE(b ^ 1, ck + 1);
      asm volatile("s_waitcnt vmcnt(4)" ::: "memory");   // this buf's 4 loads done
    } else {
      asm volatile("s_waitcnt vmcnt(0)" ::: "memory");
    }
    COMPUTE(b, ck);
  }

  // cross-wave reduce: wave w parks acc in its own (now idle) buffer 0 region
  float4* red = &xs[w][0][0];
  red[l * 4 + 0] = make_float4(acc[0],  acc[1],  acc[2],  acc[3]);
  red[l * 4 + 1] = make_float4(acc[4],  acc[5],  acc[6],  acc[7]);
  red[l * 4 + 2] = make_float4(acc[8],  acc[9],  acc[10], acc[11]);
  red[l * 4 + 3] = make_float4(acc[12], acc[13], acc[14], acc[15]);
  __syncthreads();

  const int rr = t >> 2, qq = t & 3;                // thread -> (row, quad)
  const int grow = rbase + rr;
  if (grow < N_NODES) {
    const int s = rr * 4 + qq;
    float4 a = xs[0][0][s], b4 = xs[1][0][s], c4 = xs[2][0][s], d4 = xs[3][0][s];
    float4 o = make_float4(a.x + b4.x + c4.x + d4.x, a.y + b4.y + c4.y + d4.y,
                           a.z + b4.z + c4.z + d4.z, a.w + b4.w + c4.w + d4.w);
    ((float4*)xw)[(size_t)grow * 4 + qq] = o;
  }
}

// ---------------------------------------------------------------------------
// Bucket edges by row>>7 (782 buckets of 128 rows). Per 4096-edge block:
// LDS stash + LDS histogram, ~780 block-aggregated global cursor atomics,
// then scatter of packed {col | (row&127)<<20, val_bits} into bucket slots.
__global__ __launch_bounds__(256)
void k_binscatter(const int* __restrict__ rows, const int* __restrict__ cols,
                  const float* __restrict__ vals, int* __restrict__ cursor,
                  int2* __restrict__ binned) {
  __shared__ int2 stash[CHUNK];                 // 32 KB
  __shared__ unsigned short sbuck[CHUNK];       // 8 KB
  __shared__ int hist[NBUCK];                   // 3.1 KB
  __shared__ int base[NBUCK];                   // 3.1 KB
  const int t = threadIdx.x;
  const int e0 = blockIdx.x * CHUNK;
  const int nv = (N_EDGES - e0 < CHUNK) ? (N_EDGES - e0) : CHUNK;

  for (int b = t; b < NBUCK; b += 256) hist[b] = 0;
  __syncthreads();

#pragma unroll
  for (int i = 0; i < CHUNK / 256; ++i) {
    const int idx = i * 256 + t;
    if (idx < nv) {
      const int e = e0 + idx;
      const int r = rows[e], c = cols[e];
      const float v = vals[e];
      const int b = r >> 7;
      stash[idx] = make_int2(c | ((r & 127) << 20), __float_as_int(v));
      sbuck[idx] = (unsigned short)b;
      atomicAdd(&hist[b], 1);                   // LDS atomic
    }
  }
  __syncthreads();

  for (int b = t; b < NBUCK; b += 256) {
    const int h = hist[b];
    base[b] = (h > 0) ? atomicAdd(&cursor[b], h) : 0;   // global, aggregated
    hist[b] = 0;                                         // reuse as rank ctr
  }
  __syncthreads();

#pragma unroll
  for (int i = 0; i < CHUNK / 256; ++i) {
    const int idx = i * 256 + t;
    if (idx < nv) {
      const int b = sbuck[idx];
      const int off = base[b] + atomicAdd(&hist[b], 1);  // LDS atomic
      if (off < BCAP) binned[(size_t)b * BCAP + off] = stash[idx];
    }
  }
}

// ---------------------------------------------------------------------------
// Per-bucket in-place counting sort -> bucket-local CSR + row_beg/row_end.
// All LDS: stash + rank via LDS atomics + 128-wide scan. Zero global atomics.
__global__ __launch_bounds__(256)
void k_localcsr(int2* __restrict__ binned, const int* __restrict__ cursor,
                int* __restrict__ row_beg, int* __restrict__ row_end) {
  __shared__ int2 stash[BCAP];                  // 40 KB
  __shared__ unsigned short rk[BCAP];           // 10 KB
  __shared__ int hist[128];
  __shared__ int pfx[128];
  const int t = threadIdx.x;
  const int b = blockIdx.x;
  const int raw = cursor[b];
  const int cnt = raw < BCAP ? raw : BCAP;
  int2* ep = binned + (size_t)b * BCAP;

  if (t < 128) hist[t] = 0;
  __syncthreads();

  for (int i = t; i < cnt; i += 256) {
    const int2 e = ep[i];
    stash[i] = e;
    rk[i] = (unsigned short)atomicAdd(&hist[(e.x >> 20) & 127], 1);
  }
  __syncthreads();

  if (t < 128) pfx[t] = hist[t];
  __syncthreads();
#pragma unroll
  for (int off = 1; off < 128; off <<= 1) {     // inclusive Hillis-Steele
    int add = (t >= off && t < 128) ? pfx[t - off] : 0;
    __syncthreads();
    if (t < 128) pfx[t] += add;
    __syncthreads();
  }

  if (t < 128) {
    const int r = b * 128 + t;
    if (r < N_NODES) {
      const int beg = b * BCAP + pfx[t] - hist[t];      // exclusive prefix
      row_beg[r] = beg;
      row_end[r] = beg + hist[t];
    }
  }
  __syncthreads();

  for (int i = t; i < cnt; i += 256) {
    const int2 e = stash[i];
    const int row = (e.x >> 20) & 127;
    ep[pfx[row] - hist[row] + (int)rk[i]] = e;
  }
}

// ---------------------------------------------------------------------------
// Fused layer-1 tail: gather-SPMM + bias + relu + (.) @ W2 -> hw1[r].
// 16 lanes per row (lane = hidden channel), 16 rows per 256-thread block.
__global__ __launch_bounds__(256)
void k_fused1(const int2* __restrict__ binned, const int* __restrict__ row_beg,
              const int* __restrict__ row_end, const float* __restrict__ xw,
              const float* __restrict__ b1, const float* __restrict__ W2,
              float* __restrict__ hw1) {
  const int t = threadIdx.x;
  const int lane16 = t & 15;
  const int r = blockIdx.x * 16 + (t >> 4);
  if (r >= N_NODES) return;
  const int s = row_beg[r], e = row_end[r];
  float a0 = 0.f, a1 = 0.f;
  int i = s;
  for (; i + 1 < e; i += 2) {                        // 2 independent chains
    int2 ea = binned[i], eb = binned[i + 1];
    a0 = fmaf(__int_as_float(ea.y), xw[(size_t)(ea.x & 0xFFFFF) * 16 + lane16], a0);
    a1 = fmaf(__int_as_float(eb.y), xw[(size_t)(eb.x & 0xFFFFF) * 16 + lane16], a1);
  }
  if (i < e) {
    int2 ea = binned[i];
    a0 = fmaf(__int_as_float(ea.y), xw[(size_t)(ea.x & 0xFFFFF) * 16 + lane16], a0);
  }
  float h = fmaxf(a0 + a1 + b1[lane16], 0.f);
  float p = h * W2[lane16];
#pragma unroll
  for (int m = 8; m >= 1; m >>= 1) p += __shfl_xor(p, m, 16);
  if (lane16 == 0) hw1[r] = p;
}

// ---------------------------------------------------------------------------
// Fused layer-2 tail: gather-SPMM on scalars + bias + sigmoid -> out[r].
__global__ __launch_bounds__(256)
void k_fused2(const int2* __restrict__ binned, const int* __restrict__ row_beg,
              const int* __restrict__ row_end, const float* __restrict__ hw1,
              const float* __restrict__ b2, float* __restrict__ out) {
  const int t = threadIdx.x;
  const int lane16 = t & 15;
  const int r = blockIdx.x * 16 + (t >> 4);
  if (r >= N_NODES) return;
  const int s = row_beg[r], e = row_end[r];
  float acc = 0.f;
  for (int i = s + lane16; i < e; i += 16) {
    int2 ev = binned[i];
    acc = fmaf(__int_as_float(ev.y), hw1[ev.x & 0xFFFFF], acc);
  }
#pragma unroll
  for (int m = 8; m >= 1; m >>= 1) acc += __shfl_xor(acc, m, 16);
  if (lane16 == 0) out[r] = 1.f / (1.f + expf(-(acc + b2[0])));
}

// ---------------------------------------------------------------------------
extern "C" void kernel_launch(void* const* d_in, const int* in_sizes, int n_in,
                              void* d_out, int out_size, void* d_ws, size_t ws_size,
                              hipStream_t stream) {
  const float* x    = (const float*)d_in[0];
  const float* vals = (const float*)d_in[1];
  const float* W1   = (const float*)d_in[2];
  const float* b1   = (const float*)d_in[3];
  const float* W2   = (const float*)d_in[4];
  const float* b2   = (const float*)d_in[5];
  const int*   rows = (const int*)d_in[6];
  const int*   cols = (const int*)d_in[7];
  float* out = (float*)d_out;

  // workspace: xw[N*16]f (6.4MB) | binned[NBUCK*BCAP]int2 (32.0MB) |
  //   cursor[NBUCK]i | row_beg[N]i | row_end[N]i | hw1[N]f
  char* w = (char*)d_ws;
  float* xw      = (float*)w;  w += (size_t)N_NODES * 16 * 4;
  int2*  binned  = (int2*)w;   w += (size_t)NBUCK * BCAP * 8;
  int*   cursor  = (int*)w;    w += (size_t)((NBUCK + 3) & ~3) * 4;
  int*   row_beg = (int*)w;    w += (size_t)N_NODES * 4;
  int*   row_end = (int*)w;    w += (size_t)N_NODES * 4;
  float* hw1     = (float*)w;

  k_prep      <<<(NBUCK + 255) / 256,           256, 0, stream>>>(cursor);
  k_gemm1     <<<(N_NODES + 63) / 64,           256, 0, stream>>>(x, W1, xw);
  k_binscatter<<<(N_EDGES + CHUNK - 1) / CHUNK, 256, 0, stream>>>(rows, cols, vals,
                                                                  cursor, binned);
  k_localcsr  <<<NBUCK,                         256, 0, stream>>>(binned, cursor,
                                                                  row_beg, row_end);
  k_fused1    <<<(N_NODES + 15) / 16,           256, 0, stream>>>(binned, row_beg,
                                                                  row_end, xw, b1,
                                                                  W2, hw1);
  k_fused2    <<<(N_NODES + 15) / 16,           256, 0, stream>>>(binned, row_beg,
                                                                  row_end, hw1,
                                                                  b2, out);
}

// Round 8
// 209.364 us; speedup vs baseline: 2.9057x; 1.0417x over previous
//
#include <hip/hip_runtime.h>
#include <cstdint>
#include <cstddef>

#define N_NODES 100000
#define N_EDGES 3200000
#define N_FEAT  512
#define HIDDEN  16
#define NBUCK   ((N_NODES + 127) / 128)   // 782 buckets of 128 rows
#define BCAP    5120                      // slots/bucket; mean 4096, +16 sigma
#define CHUNK   4096                      // edges per binscatter block
#define NGB     ((N_NODES + 63) / 64)     // 1563 gemm blocks (64 rows each)

// ---------------------------------------------------------------------------
// async global -> LDS, 16B per lane. LDS dest is wave-uniform base + lane*16.
__device__ __forceinline__ void gload_lds16(const float* g, void* lds) {
  __builtin_amdgcn_global_load_lds(
      (const __attribute__((address_space(1))) void*)g,
      (__attribute__((address_space(3))) void*)lds, 16, 0, 0);
}

// ---------------------------------------------------------------------------
// Prep: zero bucket cursors (replaces rocclr fillBuffer).
__global__ __launch_bounds__(256)
void k_prep(int* __restrict__ cursor) {
  const int i = blockIdx.x * 256 + threadIdx.x;
  if (i < NBUCK) cursor[i] = 0;
}

// ---------------------------------------------------------------------------
// Bucket edges by row>>7 (782 buckets of 128 rows). Per 4096-edge block:
// LDS stash + LDS histogram, ~780 block-aggregated global cursor atomics,
// then scatter of packed {col | (row&127)<<20, val_bits} into bucket slots.
__global__ __launch_bounds__(256)
void k_binscatter(const int* __restrict__ rows, const int* __restrict__ cols,
                  const float* __restrict__ vals, int* __restrict__ cursor,
                  int2* __restrict__ binned) {
  __shared__ int2 stash[CHUNK];                 // 32 KB
  __shared__ unsigned short sbuck[CHUNK];       // 8 KB
  __shared__ int hist[NBUCK];                   // 3.1 KB
  __shared__ int base[NBUCK];                   // 3.1 KB
  const int t = threadIdx.x;
  const int e0 = blockIdx.x * CHUNK;
  const int nv = (N_EDGES - e0 < CHUNK) ? (N_EDGES - e0) : CHUNK;

  for (int b = t; b < NBUCK; b += 256) hist[b] = 0;
  __syncthreads();

#pragma unroll
  for (int i = 0; i < CHUNK / 256; ++i) {
    const int idx = i * 256 + t;
    if (idx < nv) {
      const int e = e0 + idx;
      const int r = rows[e], c = cols[e];
      const float v = vals[e];
      const int b = r >> 7;
      stash[idx] = make_int2(c | ((r & 127) << 20), __float_as_int(v));
      sbuck[idx] = (unsigned short)b;
      atomicAdd(&hist[b], 1);                   // LDS atomic
    }
  }
  __syncthreads();

  for (int b = t; b < NBUCK; b += 256) {
    const int h = hist[b];
    base[b] = (h > 0) ? atomicAdd(&cursor[b], h) : 0;   // global, aggregated
    hist[b] = 0;                                         // reuse as rank ctr
  }
  __syncthreads();

#pragma unroll
  for (int i = 0; i < CHUNK / 256; ++i) {
    const int idx = i * 256 + t;
    if (idx < nv) {
      const int b = sbuck[idx];
      const int off = base[b] + atomicAdd(&hist[b], 1);  // LDS atomic
      if (off < BCAP) binned[(size_t)b * BCAP + off] = stash[idx];
    }
  }
}

// ---------------------------------------------------------------------------
// MEGA: blocks [0,NGB) run GEMM1; blocks [NGB,NGB+NBUCK) run localcsr-v2.
// The two halves are data-independent; co-residency overlaps gemm's HBM
// streaming with localcsr's LDS/latency work. Shared-LDS union = 32 KB so
// gemm keeps 5 blocks/CU.
//
// GEMM1: xw[r][c] = sum_k x[r][k]*W1[k][c]. 4 waves split K (128 each),
// per-wave double-buffered gload_lds stage, counted vmcnt(4), no intra-loop
// barriers; cross-wave LDS reduce at the end.
//
// localcsr-v2: per bucket, rank edges by row via LDS-atomic histogram
// (rk in LDS, 10.25 KB), 128-wide scan, then re-read binned (LLC) and write
// row-sorted edges to binned2 + emit row_beg/row_end. No 40 KB stash.
__global__ __launch_bounds__(256)
void k_mega(const float* __restrict__ x, const float* __restrict__ W1,
            float* __restrict__ xw, const int2* __restrict__ binned,
            const int* __restrict__ cursor, int2* __restrict__ binned2,
            int* __restrict__ row_beg, int* __restrict__ row_end) {
  __shared__ __align__(16) char smem[32768];
  const int t = threadIdx.x;

  if (blockIdx.x < NGB) {
    // ---------------- GEMM1 ----------------
    float4 (*xs)[2][256] = reinterpret_cast<float4 (*)[2][256]>(smem);
    const int l = t & 63;
    const int w = __builtin_amdgcn_readfirstlane(t >> 6);
    const int rbase = blockIdx.x * 64;
    const int kbase0 = w * 128;

    float acc[16];
#pragma unroll
    for (int c = 0; c < 16; ++c) acc[c] = 0.f;

    const int sq   = ((l & 3) ^ ((l >> 3) & 3)) * 4;  // source quad (floats)
    const int srow = l >> 2;

    auto STAGE = [&](int b, int ck) {
      const int kb = kbase0 + ck * 16;
#pragma unroll
      for (int i = 0; i < 4; ++i) {
        int grow = rbase + i * 16 + srow;
        if (grow >= N_NODES) grow = N_NODES - 1;      // clamp: fixed instr count
        gload_lds16(x + (size_t)grow * N_FEAT + kb + sq, &xs[w][b][i * 64]);
      }
    };

    const int rsw = (l >> 1) & 3;
    auto COMPUTE = [&](int b, int ck) {
      const int kb = kbase0 + ck * 16;
#pragma unroll
      for (int q = 0; q < 4; ++q) {
        float4 xv = xs[w][b][l * 4 + (q ^ rsw)];
        float xe[4] = {xv.x, xv.y, xv.z, xv.w};
#pragma unroll
        for (int j = 0; j < 4; ++j) {
          const float* wrow = W1 + (size_t)(kb + q * 4 + j) * 16; // s_load
#pragma unroll
          for (int c = 0; c < 16; ++c)
            acc[c] = fmaf(xe[j], wrow[c], acc[c]);
        }
      }
    };

    STAGE(0, 0);
#pragma unroll 1
    for (int ck = 0; ck < 8; ++ck) {
      const int b = ck & 1;
      if (ck + 1 < 8) {
        STAGE(b ^ 1, ck + 1);
        asm volatile("s_waitcnt vmcnt(4)" ::: "memory");
      } else {
        asm volatile("s_waitcnt vmcnt(0)" ::: "memory");
      }
      COMPUTE(b, ck);
    }

    float4* red = &xs[w][0][0];
    red[l * 4 + 0] = make_float4(acc[0],  acc[1],  acc[2],  acc[3]);
    red[l * 4 + 1] = make_float4(acc[4],  acc[5],  acc[6],  acc[7]);
    red[l * 4 + 2] = make_float4(acc[8],  acc[9],  acc[10], acc[11]);
    red[l * 4 + 3] = make_float4(acc[12], acc[13], acc[14], acc[15]);
    __syncthreads();

    const int rr = t >> 2, qq = t & 3;
    const int grow = rbase + rr;
    if (grow < N_NODES) {
      const int s = rr * 4 + qq;
      float4 a = xs[0][0][s], b4 = xs[1][0][s], c4 = xs[2][0][s], d4 = xs[3][0][s];
      float4 o = make_float4(a.x + b4.x + c4.x + d4.x, a.y + b4.y + c4.y + d4.y,
                             a.z + b4.z + c4.z + d4.z, a.w + b4.w + c4.w + d4.w);
      ((float4*)xw)[(size_t)grow * 4 + qq] = o;
    }
  } else {
    // ---------------- localcsr-v2 ----------------
    unsigned short* rk  = (unsigned short*)smem;          // 10.25 KB
    int*            hist = (int*)(smem + BCAP * 2);       // 512 B
    int*            pfx  = (int*)(smem + BCAP * 2 + 512); // 512 B
    const int b = blockIdx.x - NGB;
    const int raw = cursor[b];
    const int cnt = raw < BCAP ? raw : BCAP;
    const int2* ep = binned + (size_t)b * BCAP;
    int2* eq = binned2 + (size_t)b * BCAP;

    if (t < 128) hist[t] = 0;
    __syncthreads();

    for (int i = t; i < cnt; i += 256) {
      const int row = (ep[i].x >> 20) & 127;
      rk[i] = (unsigned short)atomicAdd(&hist[row], 1);
    }
    __syncthreads();

    if (t < 128) pfx[t] = hist[t];
    __syncthreads();
#pragma unroll
    for (int off = 1; off < 128; off <<= 1) {   // inclusive Hillis-Steele
      int add = (t >= off && t < 128) ? pfx[t - off] : 0;
      __syncthreads();
      if (t < 128) pfx[t] += add;
      __syncthreads();
    }

    if (t < 128) {
      const int r = b * 128 + t;
      if (r < N_NODES) {
        const int beg = b * BCAP + pfx[t] - hist[t];     // exclusive prefix
        row_beg[r] = beg;
        row_end[r] = beg + hist[t];
      }
    }
    __syncthreads();

    for (int i = t; i < cnt; i += 256) {
      const int2 e = ep[i];                              // LLC re-read
      const int row = (e.x >> 20) & 127;
      eq[pfx[row] - hist[row] + (int)rk[i]] = e;
    }
  }
}

// ---------------------------------------------------------------------------
// Fused layer-1 tail: gather-SPMM + bias + relu + (.) @ W2 -> hw1[r].
// 16 lanes per row (lane = hidden channel), 16 rows per 256-thread block.
__global__ __launch_bounds__(256)
void k_fused1(const int2* __restrict__ binned2, const int* __restrict__ row_beg,
              const int* __restrict__ row_end, const float* __restrict__ xw,
              const float* __restrict__ b1, const float* __restrict__ W2,
              float* __restrict__ hw1) {
  const int t = threadIdx.x;
  const int lane16 = t & 15;
  const int r = blockIdx.x * 16 + (t >> 4);
  if (r >= N_NODES) return;
  const int s = row_beg[r], e = row_end[r];
  float a0 = 0.f, a1 = 0.f;
  int i = s;
  for (; i + 1 < e; i += 2) {                        // 2 independent chains
    int2 ea = binned2[i], eb = binned2[i + 1];
    a0 = fmaf(__int_as_float(ea.y), xw[(size_t)(ea.x & 0xFFFFF) * 16 + lane16], a0);
    a1 = fmaf(__int_as_float(eb.y), xw[(size_t)(eb.x & 0xFFFFF) * 16 + lane16], a1);
  }
  if (i < e) {
    int2 ea = binned2[i];
    a0 = fmaf(__int_as_float(ea.y), xw[(size_t)(ea.x & 0xFFFFF) * 16 + lane16], a0);
  }
  float h = fmaxf(a0 + a1 + b1[lane16], 0.f);
  float p = h * W2[lane16];
#pragma unroll
  for (int m = 8; m >= 1; m >>= 1) p += __shfl_xor(p, m, 16);
  if (lane16 == 0) hw1[r] = p;
}

// ---------------------------------------------------------------------------
// Fused layer-2 tail: gather-SPMM on scalars + bias + sigmoid -> out[r].
__global__ __launch_bounds__(256)
void k_fused2(const int2* __restrict__ binned2, const int* __restrict__ row_beg,
              const int* __restrict__ row_end, const float* __restrict__ hw1,
              const float* __restrict__ b2, float* __restrict__ out) {
  const int t = threadIdx.x;
  const int lane16 = t & 15;
  const int r = blockIdx.x * 16 + (t >> 4);
  if (r >= N_NODES) return;
  const int s = row_beg[r], e = row_end[r];
  float acc = 0.f;
  for (int i = s + lane16; i < e; i += 16) {
    int2 ev = binned2[i];
    acc = fmaf(__int_as_float(ev.y), hw1[ev.x & 0xFFFFF], acc);
  }
#pragma unroll
  for (int m = 8; m >= 1; m >>= 1) acc += __shfl_xor(acc, m, 16);
  if (lane16 == 0) out[r] = 1.f / (1.f + expf(-(acc + b2[0])));
}

// ---------------------------------------------------------------------------
extern "C" void kernel_launch(void* const* d_in, const int* in_sizes, int n_in,
                              void* d_out, int out_size, void* d_ws, size_t ws_size,
                              hipStream_t stream) {
  const float* x    = (const float*)d_in[0];
  const float* vals = (const float*)d_in[1];
  const float* W1   = (const float*)d_in[2];
  const float* b1   = (const float*)d_in[3];
  const float* W2   = (const float*)d_in[4];
  const float* b2   = (const float*)d_in[5];
  const int*   rows = (const int*)d_in[6];
  const int*   cols = (const int*)d_in[7];
  float* out = (float*)d_out;

  // workspace (~66 MB of the ~800 MB d_ws):
  // xw[N*16]f | binned[NBUCK*BCAP]int2 | binned2[NBUCK*BCAP]int2 |
  // cursor[NBUCK]i | row_beg[N]i | row_end[N]i | hw1[N]f
  char* w = (char*)d_ws;
  float* xw      = (float*)w;  w += (size_t)N_NODES * 16 * 4;
  int2*  binned  = (int2*)w;   w += (size_t)NBUCK * BCAP * 8;
  int2*  binned2 = (int2*)w;   w += (size_t)NBUCK * BCAP * 8;
  int*   cursor  = (int*)w;    w += (size_t)((NBUCK + 3) & ~3) * 4;
  int*   row_beg = (int*)w;    w += (size_t)N_NODES * 4;
  int*   row_end = (int*)w;    w += (size_t)N_NODES * 4;
  float* hw1     = (float*)w;

  k_prep      <<<(NBUCK + 255) / 256,           256, 0, stream>>>(cursor);
  k_binscatter<<<(N_EDGES + CHUNK - 1) / CHUNK, 256, 0, stream>>>(rows, cols, vals,
                                                                  cursor, binned);
  k_mega      <<<NGB + NBUCK,                   256, 0, stream>>>(x, W1, xw,
                                                                  binned, cursor,
                                                                  binned2, row_beg,
                                                                  row_end);
  k_fused1    <<<(N_NODES + 15) / 16,           256, 0, stream>>>(binned2, row_beg,
                                                                  row_end, xw, b1,
                                                                  W2, hw1);
  k_fused2    <<<(N_NODES + 15) / 16,           256, 0, stream>>>(binned2, row_beg,
                                                                  row_end, hw1,
                                                                  b2, out);
}

// Round 9
// 202.263 us; speedup vs baseline: 3.0077x; 1.0351x over previous
//
#include <hip/hip_runtime.h>
#include <cstdint>
#include <cstddef>

#define N_NODES 100000
#define N_EDGES 3200000
#define N_FEAT  512
#define HIDDEN  16
#define NBUCK   ((N_NODES + 127) / 128)   // 782 buckets of 128 rows
#define BCAP    5120                      // slots/bucket; mean 4096, +16 sigma
#define CHUNK   2048                      // edges per binscatter role-block
#define NGB     ((N_NODES + 63) / 64)     // 1563 gemm blocks (64 rows each)
#define NBS     ((N_EDGES + CHUNK - 1) / CHUNK)  // 1563 binscatter blocks

static_assert(NGB == NBS, "parity interleave requires equal role counts");

// ---------------------------------------------------------------------------
// async global -> LDS, 16B per lane. LDS dest is wave-uniform base + lane*16.
__device__ __forceinline__ void gload_lds16(const float* g, void* lds) {
  __builtin_amdgcn_global_load_lds(
      (const __attribute__((address_space(1))) void*)g,
      (__attribute__((address_space(3))) void*)lds, 16, 0, 0);
}

// ---------------------------------------------------------------------------
// Prep: zero bucket cursors (replaces rocclr fillBuffer).
__global__ __launch_bounds__(256)
void k_prep(int* __restrict__ cursor) {
  const int i = blockIdx.x * 256 + threadIdx.x;
  if (i < NBUCK) cursor[i] = 0;
}

// ---------------------------------------------------------------------------
// MEGA2: parity-interleaved roles for true co-residency from dispatch 0.
//   even blocks -> GEMM1 (HBM-BW-bound),  gid = bid >> 1
//   odd  blocks -> binscatter (LDS/atomic-bound), bsid = bid >> 1
// Union LDS = 32 KB -> 5 blocks/CU.
//
// GEMM1: xw[r][c] = sum_k x[r][k]*W1[k][c]. 4 waves split K (128 each),
// per-wave double-buffered gload_lds stage, counted vmcnt(4), no intra-loop
// barriers; cross-wave LDS reduce at the end.
//
// binscatter: bucket edges by row>>7. Per 2048-edge block: LDS stash +
// LDS histogram, ~780 block-aggregated global cursor atomics, then scatter
// of packed {col | (row&127)<<20, val_bits} into bucket slots.
__global__ __launch_bounds__(256)
void k_mega2(const float* __restrict__ x, const float* __restrict__ W1,
             float* __restrict__ xw, const int* __restrict__ rows,
             const int* __restrict__ cols, const float* __restrict__ vals,
             int* __restrict__ cursor, int2* __restrict__ binned) {
  __shared__ __align__(16) char smem[32768];
  const int t = threadIdx.x;

  if ((blockIdx.x & 1) == 0) {
    // ---------------- GEMM1 ----------------
    float4 (*xs)[2][256] = reinterpret_cast<float4 (*)[2][256]>(smem);
    const int l = t & 63;
    const int w = __builtin_amdgcn_readfirstlane(t >> 6);
    const int rbase = (blockIdx.x >> 1) * 64;
    const int kbase0 = w * 128;

    float acc[16];
#pragma unroll
    for (int c = 0; c < 16; ++c) acc[c] = 0.f;

    const int sq   = ((l & 3) ^ ((l >> 3) & 3)) * 4;  // source quad (floats)
    const int srow = l >> 2;

    auto STAGE = [&](int b, int ck) {
      const int kb = kbase0 + ck * 16;
#pragma unroll
      for (int i = 0; i < 4; ++i) {
        int grow = rbase + i * 16 + srow;
        if (grow >= N_NODES) grow = N_NODES - 1;      // clamp: fixed instr count
        gload_lds16(x + (size_t)grow * N_FEAT + kb + sq, &xs[w][b][i * 64]);
      }
    };

    const int rsw = (l >> 1) & 3;
    auto COMPUTE = [&](int b, int ck) {
      const int kb = kbase0 + ck * 16;
#pragma unroll
      for (int q = 0; q < 4; ++q) {
        float4 xv = xs[w][b][l * 4 + (q ^ rsw)];
        float xe[4] = {xv.x, xv.y, xv.z, xv.w};
#pragma unroll
        for (int j = 0; j < 4; ++j) {
          const float* wrow = W1 + (size_t)(kb + q * 4 + j) * 16; // s_load
#pragma unroll
          for (int c = 0; c < 16; ++c)
            acc[c] = fmaf(xe[j], wrow[c], acc[c]);
        }
      }
    };

    STAGE(0, 0);
#pragma unroll 1
    for (int ck = 0; ck < 8; ++ck) {
      const int b = ck & 1;
      if (ck + 1 < 8) {
        STAGE(b ^ 1, ck + 1);
        asm volatile("s_waitcnt vmcnt(4)" ::: "memory");
      } else {
        asm volatile("s_waitcnt vmcnt(0)" ::: "memory");
      }
      COMPUTE(b, ck);
    }

    float4* red = &xs[w][0][0];
    red[l * 4 + 0] = make_float4(acc[0],  acc[1],  acc[2],  acc[3]);
    red[l * 4 + 1] = make_float4(acc[4],  acc[5],  acc[6],  acc[7]);
    red[l * 4 + 2] = make_float4(acc[8],  acc[9],  acc[10], acc[11]);
    red[l * 4 + 3] = make_float4(acc[12], acc[13], acc[14], acc[15]);
    __syncthreads();

    const int rr = t >> 2, qq = t & 3;
    const int grow = rbase + rr;
    if (grow < N_NODES) {
      const int s = rr * 4 + qq;
      float4 a = xs[0][0][s], b4 = xs[1][0][s], c4 = xs[2][0][s], d4 = xs[3][0][s];
      float4 o = make_float4(a.x + b4.x + c4.x + d4.x, a.y + b4.y + c4.y + d4.y,
                             a.z + b4.z + c4.z + d4.z, a.w + b4.w + c4.w + d4.w);
      ((float4*)xw)[(size_t)grow * 4 + qq] = o;
    }
  } else {
    // ---------------- binscatter ----------------
    int2*           stash = (int2*)smem;                       // 16 KB
    unsigned short* sbuck = (unsigned short*)(smem + 16384);   // 4 KB
    int*            hist  = (int*)(smem + 16384 + 4096);       // 3.13 KB
    int*            base  = (int*)(smem + 16384 + 4096 + 4 * NBUCK);
    const int e0 = (blockIdx.x >> 1) * CHUNK;
    const int nv = (N_EDGES - e0 < CHUNK) ? (N_EDGES - e0) : CHUNK;

    for (int b = t; b < NBUCK; b += 256) hist[b] = 0;
    __syncthreads();

#pragma unroll
    for (int i = 0; i < CHUNK / 256; ++i) {
      const int idx = i * 256 + t;
      if (idx < nv) {
        const int e = e0 + idx;
        const int r = rows[e], c = cols[e];
        const float v = vals[e];
        const int b = r >> 7;
        stash[idx] = make_int2(c | ((r & 127) << 20), __float_as_int(v));
        sbuck[idx] = (unsigned short)b;
        atomicAdd(&hist[b], 1);                   // LDS atomic
      }
    }
    __syncthreads();

    for (int b = t; b < NBUCK; b += 256) {
      const int h = hist[b];
      base[b] = (h > 0) ? atomicAdd(&cursor[b], h) : 0;   // global, aggregated
      hist[b] = 0;                                         // reuse as rank ctr
    }
    __syncthreads();

#pragma unroll
    for (int i = 0; i < CHUNK / 256; ++i) {
      const int idx = i * 256 + t;
      if (idx < nv) {
        const int b = sbuck[idx];
        const int off = base[b] + atomicAdd(&hist[b], 1);  // LDS atomic
        if (off < BCAP) binned[(size_t)b * BCAP + off] = stash[idx];
      }
    }
  }
}

// ---------------------------------------------------------------------------
// Per-bucket counting sort (v2, low-LDS): rank via LDS-atomic histogram,
// 128-wide scan, re-read binned (LLC) and write row-sorted edges to binned2;
// emit row_beg/row_end. Zero global atomics.
__global__ __launch_bounds__(256)
void k_localcsr(const int2* __restrict__ binned, const int* __restrict__ cursor,
                int2* __restrict__ binned2, int* __restrict__ row_beg,
                int* __restrict__ row_end) {
  __shared__ unsigned short rk[BCAP];           // 10.25 KB
  __shared__ int hist[128];
  __shared__ int pfx[128];
  const int t = threadIdx.x;
  const int b = blockIdx.x;
  const int raw = cursor[b];
  const int cnt = raw < BCAP ? raw : BCAP;
  const int2* ep = binned + (size_t)b * BCAP;
  int2* eq = binned2 + (size_t)b * BCAP;

  if (t < 128) hist[t] = 0;
  __syncthreads();

  for (int i = t; i < cnt; i += 256) {
    const int row = (ep[i].x >> 20) & 127;
    rk[i] = (unsigned short)atomicAdd(&hist[row], 1);
  }
  __syncthreads();

  if (t < 128) pfx[t] = hist[t];
  __syncthreads();
#pragma unroll
  for (int off = 1; off < 128; off <<= 1) {     // inclusive Hillis-Steele
    int add = (t >= off && t < 128) ? pfx[t - off] : 0;
    __syncthreads();
    if (t < 128) pfx[t] += add;
    __syncthreads();
  }

  if (t < 128) {
    const int r = b * 128 + t;
    if (r < N_NODES) {
      const int beg = b * BCAP + pfx[t] - hist[t];      // exclusive prefix
      row_beg[r] = beg;
      row_end[r] = beg + hist[t];
    }
  }
  __syncthreads();

  for (int i = t; i < cnt; i += 256) {
    const int2 e = ep[i];                               // LLC re-read
    const int row = (e.x >> 20) & 127;
    eq[pfx[row] - hist[row] + (int)rk[i]] = e;
  }
}

// ---------------------------------------------------------------------------
// Fused layer-1 tail: gather-SPMM + bias + relu + (.) @ W2 -> hw1[r].
// 16 lanes per row (lane = hidden channel), 16 rows per 256-thread block.
__global__ __launch_bounds__(256)
void k_fused1(const int2* __restrict__ binned2, const int* __restrict__ row_beg,
              const int* __restrict__ row_end, const float* __restrict__ xw,
              const float* __restrict__ b1, const float* __restrict__ W2,
              float* __restrict__ hw1) {
  const int t = threadIdx.x;
  const int lane16 = t & 15;
  const int r = blockIdx.x * 16 + (t >> 4);
  if (r >= N_NODES) return;
  const int s = row_beg[r], e = row_end[r];
  float a0 = 0.f, a1 = 0.f;
  int i = s;
  for (; i + 1 < e; i += 2) {                        // 2 independent chains
    int2 ea = binned2[i], eb = binned2[i + 1];
    a0 = fmaf(__int_as_float(ea.y), xw[(size_t)(ea.x & 0xFFFFF) * 16 + lane16], a0);
    a1 = fmaf(__int_as_float(eb.y), xw[(size_t)(eb.x & 0xFFFFF) * 16 + lane16], a1);
  }
  if (i < e) {
    int2 ea = binned2[i];
    a0 = fmaf(__int_as_float(ea.y), xw[(size_t)(ea.x & 0xFFFFF) * 16 + lane16], a0);
  }
  float h = fmaxf(a0 + a1 + b1[lane16], 0.f);
  float p = h * W2[lane16];
#pragma unroll
  for (int m = 8; m >= 1; m >>= 1) p += __shfl_xor(p, m, 16);
  if (lane16 == 0) hw1[r] = p;
}

// ---------------------------------------------------------------------------
// Fused layer-2 tail: gather-SPMM on scalars + bias + sigmoid -> out[r].
__global__ __launch_bounds__(256)
void k_fused2(const int2* __restrict__ binned2, const int* __restrict__ row_beg,
              const int* __restrict__ row_end, const float* __restrict__ hw1,
              const float* __restrict__ b2, float* __restrict__ out) {
  const int t = threadIdx.x;
  const int lane16 = t & 15;
  const int r = blockIdx.x * 16 + (t >> 4);
  if (r >= N_NODES) return;
  const int s = row_beg[r], e = row_end[r];
  float acc = 0.f;
  for (int i = s + lane16; i < e; i += 16) {
    int2 ev = binned2[i];
    acc = fmaf(__int_as_float(ev.y), hw1[ev.x & 0xFFFFF], acc);
  }
#pragma unroll
  for (int m = 8; m >= 1; m >>= 1) acc += __shfl_xor(acc, m, 16);
  if (lane16 == 0) out[r] = 1.f / (1.f + expf(-(acc + b2[0])));
}

// ---------------------------------------------------------------------------
extern "C" void kernel_launch(void* const* d_in, const int* in_sizes, int n_in,
                              void* d_out, int out_size, void* d_ws, size_t ws_size,
                              hipStream_t stream) {
  const float* x    = (const float*)d_in[0];
  const float* vals = (const float*)d_in[1];
  const float* W1   = (const float*)d_in[2];
  const float* b1   = (const float*)d_in[3];
  const float* W2   = (const float*)d_in[4];
  const float* b2   = (const float*)d_in[5];
  const int*   rows = (const int*)d_in[6];
  const int*   cols = (const int*)d_in[7];
  float* out = (float*)d_out;

  // workspace (~66 MB of the ~800 MB d_ws):
  // xw[N*16]f | binned[NBUCK*BCAP]int2 | binned2[NBUCK*BCAP]int2 |
  // cursor[NBUCK]i | row_beg[N]i | row_end[N]i | hw1[N]f
  char* w = (char*)d_ws;
  float* xw      = (float*)w;  w += (size_t)N_NODES * 16 * 4;
  int2*  binned  = (int2*)w;   w += (size_t)NBUCK * BCAP * 8;
  int2*  binned2 = (int2*)w;   w += (size_t)NBUCK * BCAP * 8;
  int*   cursor  = (int*)w;    w += (size_t)((NBUCK + 3) & ~3) * 4;
  int*   row_beg = (int*)w;    w += (size_t)N_NODES * 4;
  int*   row_end = (int*)w;    w += (size_t)N_NODES * 4;
  float* hw1     = (float*)w;

  k_prep   <<<(NBUCK + 255) / 256, 256, 0, stream>>>(cursor);
  k_mega2  <<<NGB + NBS,           256, 0, stream>>>(x, W1, xw, rows, cols, vals,
                                                     cursor, binned);
  k_localcsr<<<NBUCK,              256, 0, stream>>>(binned, cursor, binned2,
                                                     row_beg, row_end);
  k_fused1 <<<(N_NODES + 15) / 16, 256, 0, stream>>>(binned2, row_beg, row_end,
                                                     xw, b1, W2, hw1);
  k_fused2 <<<(N_NODES + 15) / 16, 256, 0, stream>>>(binned2, row_beg, row_end,
                                                     hw1, b2, out);
}